// Round 2
// baseline (1062.971 us; speedup 1.0000x reference)
//
#include <hip/hip_runtime.h>
#include <math.h>

#define HDIM 4096
#define EDIM 64
#define NTOP 8
#define NWAVES 8
#define KSLICE (HDIM / NWAVES)   // 512 per wave
#define KC 8

// One block = 512 threads = 8 waves, handles 64 rows (lane = row-in-tile).
// Each lane accumulates all 64 expert logits for its row; K split across waves.
__global__ __launch_bounds__(512, 2)
void gating_kernel(const float* __restrict__ x,
                   const float* __restrict__ W,
                   const float* __restrict__ bias,
                   float* __restrict__ sparse_out,
                   float* __restrict__ idx_out,
                   float* __restrict__ gate_out)
{
    // 4 reduction regions, 64 rows x 64 experts each, XOR-swizzled so a
    // fixed-e access across lanes hits each bank exactly twice (free).
    __shared__ float red[4][EDIM * EDIM];   // 64 KB total

    const int lane = threadIdx.x & 63;
    const int wave = threadIdx.x >> 6;
    const int row  = blockIdx.x * 64 + lane;

    float acc[EDIM];
#pragma unroll
    for (int e = 0; e < EDIM; ++e) acc[e] = 0.0f;

    const int k0 = wave * KSLICE;
    const float* xrow  = x + (size_t)row * HDIM + k0;
    const float* wbase = W + k0;

#pragma unroll 1
    for (int kk = 0; kk < KSLICE; kk += KC) {
        float4 xa = *(const float4*)(xrow + kk);
        float4 xb = *(const float4*)(xrow + kk + 4);
#pragma unroll
        for (int e = 0; e < EDIM; ++e) {
            const float* we = wbase + e * HDIM + kk;   // wave-uniform -> s_load
            float s = acc[e];
            s = fmaf(xa.x, we[0], s);
            s = fmaf(xa.y, we[1], s);
            s = fmaf(xa.z, we[2], s);
            s = fmaf(xa.w, we[3], s);
            s = fmaf(xb.x, we[4], s);
            s = fmaf(xb.y, we[5], s);
            s = fmaf(xb.z, we[6], s);
            s = fmaf(xb.w, we[7], s);
            acc[e] = s;
        }
    }

    const int swz = lane & 31;   // XOR swizzle key

    // Tree reduction across waves: 8 -> 4 -> 2 -> 1 (final sum in wave 0 regs)
    if (wave >= 4) {
        float* r = red[wave - 4] + lane * EDIM;
#pragma unroll
        for (int e = 0; e < EDIM; ++e) r[e ^ swz] = acc[e];
    }
    __syncthreads();
    if (wave < 4) {
        const float* r = red[wave] + lane * EDIM;
#pragma unroll
        for (int e = 0; e < EDIM; ++e) acc[e] += r[e ^ swz];
    }
    __syncthreads();
    if (wave == 2 || wave == 3) {
        float* r = red[wave - 2] + lane * EDIM;
#pragma unroll
        for (int e = 0; e < EDIM; ++e) r[e ^ swz] = acc[e];
    }
    __syncthreads();
    if (wave < 2) {
        const float* r = red[wave] + lane * EDIM;
#pragma unroll
        for (int e = 0; e < EDIM; ++e) acc[e] += r[e ^ swz];
    }
    __syncthreads();
    if (wave == 1) {
        float* r = red[0] + lane * EDIM;
#pragma unroll
        for (int e = 0; e < EDIM; ++e) r[e ^ swz] = acc[e];
    }
    __syncthreads();

    if (wave != 0) return;

    // Final add + bias (bias[e] wave-uniform -> s_load)
    {
        const float* r = red[0] + lane * EDIM;
#pragma unroll
        for (int e = 0; e < EDIM; ++e) acc[e] += r[e ^ swz] + bias[e];
    }

    // gate_logit = raw logits
    {
        float* g = gate_out + (size_t)row * EDIM;
#pragma unroll
        for (int e = 0; e < EDIM; e += 4) {
            float4 v = make_float4(acc[e], acc[e + 1], acc[e + 2], acc[e + 3]);
            *(float4*)(g + e) = v;
        }
    }

    // Top-8 selection. Strict '>' with ascending scan == jax.lax.top_k
    // tie-break (lower index first). Fully unrolled: static indexing only.
    float vals[NTOP];
    int   idxs[NTOP];
#pragma unroll
    for (int j = 0; j < NTOP; ++j) {
        float best = acc[0];
        int   bi   = 0;
#pragma unroll
        for (int e = 1; e < EDIM; ++e) {
            bool gt = acc[e] > best;
            best = gt ? acc[e] : best;
            bi   = gt ? e : bi;
        }
        vals[j] = best;
        idxs[j] = bi;
#pragma unroll
        for (int e = 0; e < EDIM; ++e)
            acc[e] = (e == bi) ? -INFINITY : acc[e];
    }

    // indices output — harness reads the whole d_out buffer as float32,
    // so indices must be stored as float VALUES, not int32 bit patterns.
    {
        float* ip = idx_out + (size_t)row * NTOP;
        *(float4*)(ip)     = make_float4((float)idxs[0], (float)idxs[1],
                                         (float)idxs[2], (float)idxs[3]);
        *(float4*)(ip + 4) = make_float4((float)idxs[4], (float)idxs[5],
                                         (float)idxs[6], (float)idxs[7]);
    }

    // softmax over the 8 selected logits (others are exp(-inf)=0)
    float m = vals[0];           // top-1 is the row max
    float p[NTOP];
    float wsum = 0.0f;
#pragma unroll
    for (int j = 0; j < NTOP; ++j) { p[j] = expf(vals[j] - m); wsum += p[j]; }
    float inv = 1.0f / wsum;
#pragma unroll
    for (int j = 0; j < NTOP; ++j) p[j] *= inv;

    // sparse_logits row: zeros except top-k positions
    {
        float* sp = sparse_out + (size_t)row * EDIM;
#pragma unroll
        for (int e = 0; e < EDIM; e += 4) {
            float vv[4];
#pragma unroll
            for (int q = 0; q < 4; ++q) {
                float t = 0.0f;
#pragma unroll
                for (int j = 0; j < NTOP; ++j)
                    t = (idxs[j] == e + q) ? p[j] : t;
                vv[q] = t;
            }
            *(float4*)(sp + e) = make_float4(vv[0], vv[1], vv[2], vv[3]);
        }
    }
}

extern "C" void kernel_launch(void* const* d_in, const int* in_sizes, int n_in,
                              void* d_out, int out_size, void* d_ws, size_t ws_size,
                              hipStream_t stream)
{
    const float* x = (const float*)d_in[0];
    const float* W = (const float*)d_in[1];
    const float* b = (const float*)d_in[2];

    const int rows = in_sizes[0] / HDIM;                 // B*S = 16384

    float* sparse = (float*)d_out;                                    // rows*64
    float* idx    = (float*)d_out + (size_t)rows * EDIM;              // rows*8
    float* gate   = (float*)d_out + (size_t)rows * EDIM
                                  + (size_t)rows * NTOP;              // rows*64

    dim3 grid(rows / 64), block(512);
    hipLaunchKernelGGL(gating_kernel, grid, block, 0, stream,
                       x, W, b, sparse, idx, gate);
}

// Round 3
// 868.145 us; speedup vs baseline: 1.2244x; 1.2244x over previous
//
#include <hip/hip_runtime.h>
#include <math.h>

#define HDIM 4096
#define EDIM 64
#define NTOP 8
#define EPW 8            // experts per wave
#define NWAVES 8         // 512 threads

// One block = 512 threads = 8 waves = 64 rows (lane = row).
// Wave w accumulates experts [8w, 8w+8) over the FULL K for its 64 rows.
// W is wave-uniform -> forced scalar (s_load, SMEM pipe, SGPR operand to
// v_fmac) via readfirstlane. x streams per-lane float4 (coalesced).
// No LDS in the main loop; 16KB LDS gathers partials for the epilogue.
__global__ __launch_bounds__(512)
void gating_kernel(const float* __restrict__ x,
                   const float* __restrict__ W,
                   const float* __restrict__ bias,
                   float* __restrict__ sparse_out,
                   float* __restrict__ idx_out,
                   float* __restrict__ gate_out)
{
    __shared__ float lg[EDIM * 64];   // [e][row-lane], 16 KB

    const int lane = threadIdx.x & 63;
    const int wave = threadIdx.x >> 6;
    const int uw   = __builtin_amdgcn_readfirstlane(wave);   // uniform wave id
    const int row  = blockIdx.x * 64 + lane;

    const float* xrow  = x + (size_t)row * HDIM;
    const float* wbase = W + (size_t)(uw * EPW) * HDIM;      // uniform pointer

    float acc[EPW];
#pragma unroll
    for (int j = 0; j < EPW; ++j) acc[j] = 0.0f;

#pragma unroll 1
    for (int k0 = 0; k0 < HDIM; k0 += 32) {
        // per-lane x chunk: 32 floats = 8 x dwordx4, issued up front
        float4 xv[8];
#pragma unroll
        for (int i = 0; i < 8; ++i)
            xv[i] = *(const float4*)(xrow + k0 + 4 * i);

#pragma unroll
        for (int i = 0; i < 8; ++i) {
#pragma unroll
            for (int e = 0; e < EPW; ++e) {
                // uniform address, constant offsets -> s_load_dwordx4 + imm
                const float4 wv = *(const float4*)(wbase + e * HDIM + k0 + 4 * i);
                float s = acc[e];
                s = fmaf(xv[i].x, wv.x, s);
                s = fmaf(xv[i].y, wv.y, s);
                s = fmaf(xv[i].z, wv.z, s);
                s = fmaf(xv[i].w, wv.w, s);
                acc[e] = s;
            }
        }
    }

    // gather partials: lg[e][lane]  (consecutive lanes -> consecutive banks)
#pragma unroll
    for (int j = 0; j < EPW; ++j)
        lg[(uw * EPW + j) * 64 + lane] = acc[j];
    __syncthreads();

    if (wave != 0) return;

    // ---- epilogue (verified in round 2): bias, gate, top-8, softmax ----
    float v[EDIM];
#pragma unroll
    for (int e = 0; e < EDIM; ++e)
        v[e] = lg[e * 64 + lane] + bias[e];   // bias[e] uniform -> s_load

    // gate_logit = raw (biased) logits
    {
        float* g = gate_out + (size_t)row * EDIM;
#pragma unroll
        for (int e = 0; e < EDIM; e += 4)
            *(float4*)(g + e) = make_float4(v[e], v[e+1], v[e+2], v[e+3]);
    }

    // Top-8: strict '>' ascending scan == jax.lax.top_k tie-break
    float vals[NTOP];
    int   idxs[NTOP];
#pragma unroll
    for (int j = 0; j < NTOP; ++j) {
        float best = v[0];
        int   bi   = 0;
#pragma unroll
        for (int e = 1; e < EDIM; ++e) {
            bool gt = v[e] > best;
            best = gt ? v[e] : best;
            bi   = gt ? e : bi;
        }
        vals[j] = best;
        idxs[j] = bi;
#pragma unroll
        for (int e = 0; e < EDIM; ++e)
            v[e] = (e == bi) ? -INFINITY : v[e];
    }

    // indices as float VALUES (harness reads whole d_out as f32)
    {
        float* ip = idx_out + (size_t)row * NTOP;
        *(float4*)(ip)     = make_float4((float)idxs[0], (float)idxs[1],
                                         (float)idxs[2], (float)idxs[3]);
        *(float4*)(ip + 4) = make_float4((float)idxs[4], (float)idxs[5],
                                         (float)idxs[6], (float)idxs[7]);
    }

    // softmax over the 8 selected logits
    float m = vals[0];
    float p[NTOP];
    float wsum = 0.0f;
#pragma unroll
    for (int j = 0; j < NTOP; ++j) { p[j] = expf(vals[j] - m); wsum += p[j]; }
    float inv = 1.0f / wsum;
#pragma unroll
    for (int j = 0; j < NTOP; ++j) p[j] *= inv;

    // sparse_logits row: zeros except top-k positions
    {
        float* sp = sparse_out + (size_t)row * EDIM;
#pragma unroll
        for (int e = 0; e < EDIM; e += 4) {
            float vv[4];
#pragma unroll
            for (int q = 0; q < 4; ++q) {
                float t = 0.0f;
#pragma unroll
                for (int j = 0; j < NTOP; ++j)
                    t = (idxs[j] == e + q) ? p[j] : t;
                vv[q] = t;
            }
            *(float4*)(sp + e) = make_float4(vv[0], vv[1], vv[2], vv[3]);
        }
    }
}

extern "C" void kernel_launch(void* const* d_in, const int* in_sizes, int n_in,
                              void* d_out, int out_size, void* d_ws, size_t ws_size,
                              hipStream_t stream)
{
    const float* x = (const float*)d_in[0];
    const float* W = (const float*)d_in[1];
    const float* b = (const float*)d_in[2];

    const int rows = in_sizes[0] / HDIM;   // B*S = 16384

    float* sparse = (float*)d_out;                                 // rows*64
    float* idx    = (float*)d_out + (size_t)rows * EDIM;           // rows*8
    float* gate   = (float*)d_out + (size_t)rows * EDIM
                                  + (size_t)rows * NTOP;           // rows*64

    dim3 grid(rows / 64), block(512);
    hipLaunchKernelGGL(gating_kernel, grid, block, 0, stream,
                       x, W, b, sparse, idx, gate);
}

// Round 4
// 603.154 us; speedup vs baseline: 1.7624x; 1.4393x over previous
//
#include <hip/hip_runtime.h>
#include <math.h>

#define HDIM 4096
#define EDIM 64
#define NTOP 8
#define KT 64                    // k-chunk
#define NC (HDIM / KT)           // 64 chunks
#define ROWS 64                  // rows per block
#define XSTRIDE 68               // padded floats per LDS row (64 + 4) -> conflict-free b128
#define LGSTRIDE 72              // epilogue [row][expert] stride

typedef float v2f __attribute__((ext_vector_type(2)));

// Block = 512 threads = 8 waves; 64 rows (lane = row). Wave w owns experts
// [8w, 8w+8): W addresses are wave-uniform -> s_load (scalar pipe, SGPR
// operands to v_pk_fma_f32). x staged global->regs->LDS (coalesced, padded,
// double-buffered); each lane reads its row via ds_read_b128.
__global__ __launch_bounds__(512, 1)
void gating_kernel(const float* __restrict__ x,
                   const float* __restrict__ W,
                   const float* __restrict__ bias,
                   float* __restrict__ sparse_out,
                   float* __restrict__ idx_out,
                   float* __restrict__ gate_out)
{
    __shared__ float SH[2 * ROWS * XSTRIDE];   // 34.8 KB; reused as lg[64][72] after

    const int t    = threadIdx.x;
    const int lane = t & 63;
    const int wave = t >> 6;
    const int uw   = __builtin_amdgcn_readfirstlane(wave);   // uniform wave id

    // staging: thread stages 32B/chunk: row srow, float4-slots {2sp, 2sp+1}
    const int srow = t >> 3;     // 0..63
    const int sp   = t & 7;      // 0..7
    const float* gx = x + ((size_t)blockIdx.x * ROWS + srow) * HDIM + sp * 8;
    float* const xdst = &SH[srow * XSTRIDE + sp * 8];

    const float* wp0 = W + (size_t)uw * 8 * HDIM;            // uniform pointer

    v2f acc[8];
#pragma unroll
    for (int e = 0; e < 8; ++e) acc[e] = (v2f){0.0f, 0.0f};

    // ---- prologue: stage chunk 0, prefetch chunk 1 into regs ----
    float4 RA = *(const float4*)(gx);
    float4 RB = *(const float4*)(gx + 4);
    *(float4*)(xdst)     = RA;
    *(float4*)(xdst + 4) = RB;
    __syncthreads();
    RA = *(const float4*)(gx + KT);
    RB = *(const float4*)(gx + KT + 4);

#pragma unroll 1
    for (int c = 0; c < NC; ++c) {
        const int nxt = (c + 1) & 1;
        if (c + 1 < NC) {          // write chunk c+1 (regs loaded last iter)
            float* d = xdst + nxt * (ROWS * XSTRIDE);
            *(float4*)(d)     = RA;
            *(float4*)(d + 4) = RB;
        }
        if (c + 2 < NC) {          // issue loads for chunk c+2
            RA = *(const float4*)(gx + (c + 2) * KT);
            RB = *(const float4*)(gx + (c + 2) * KT + 4);
        }

        // ---- compute chunk c from buf c&1 ----
        const float* xs = &SH[(c & 1) * (ROWS * XSTRIDE) + lane * XSTRIDE];
        const float* wc = wp0 + c * KT;
#pragma unroll
        for (int kv = 0; kv < KT / 4; ++kv) {
            const float4 xv = *(const float4*)(xs + kv * 4);
            const v2f xa = {xv.x, xv.y};
            const v2f xb = {xv.z, xv.w};
#pragma unroll
            for (int e = 0; e < 8; ++e) {
                const float4 wv = *(const float4*)(wc + e * HDIM + kv * 4);
                acc[e] = __builtin_elementwise_fma(xa, (v2f){wv.x, wv.y}, acc[e]);
                acc[e] = __builtin_elementwise_fma(xb, (v2f){wv.z, wv.w}, acc[e]);
            }
        }
        __syncthreads();
    }

    // ---- gather partials into lg[row][expert] (stride 72) ----
    float* lg = SH;
#pragma unroll
    for (int e = 0; e < 8; ++e)
        lg[lane * LGSTRIDE + uw * 8 + e] = acc[e].x + acc[e].y;
    __syncthreads();

    // ---- distributed epilogue: wave w handles rows [8w, 8w+8), 8 lanes/row ----
    const int rp   = lane >> 3;          // row within wave's slice
    const int part = lane & 7;           // expert octet
    const int row  = uw * 8 + rp;
    const size_t grow = (size_t)blockIdx.x * ROWS + row;

    const float* lr = &lg[row * LGSTRIDE + part * 8];
    const float4 va = *(const float4*)(lr);
    const float4 vb = *(const float4*)(lr + 4);
    float v[8] = {va.x, va.y, va.z, va.w, vb.x, vb.y, vb.z, vb.w};
    const float* bb = bias + part * 8;
#pragma unroll
    for (int j = 0; j < 8; ++j) v[j] += bb[j];

    // gate_logit = biased logits
    {
        float* g = gate_out + grow * EDIM + part * 8;
        *(float4*)(g)     = make_float4(v[0], v[1], v[2], v[3]);
        *(float4*)(g + 4) = make_float4(v[4], v[5], v[6], v[7]);
    }

    // top-8: local strict-'>' ascending scan (lowest index on ties) then
    // 8-lane butterfly argmax (ties -> lower index) == jax.lax.top_k order
    float vals[NTOP];
    int   idxs[NTOP];
#pragma unroll
    for (int k = 0; k < NTOP; ++k) {
        float bv = v[0];
        int   bi = part * 8;
#pragma unroll
        for (int i = 1; i < 8; ++i) {
            const bool g = v[i] > bv;
            bv = g ? v[i] : bv;
            bi = g ? part * 8 + i : bi;
        }
#pragma unroll
        for (int m = 1; m < 8; m <<= 1) {
            const float ov = __shfl_xor(bv, m);
            const int   oi = __shfl_xor(bi, m);
            const bool take = (ov > bv) || (ov == bv && oi < bi);
            bv = take ? ov : bv;
            bi = take ? oi : bi;
        }
        vals[k] = bv;
        idxs[k] = bi;
#pragma unroll
        for (int i = 0; i < 8; ++i)
            v[i] = (bi == part * 8 + i) ? -INFINITY : v[i];
    }

    // indices as float VALUES (harness reads d_out as f32)
    if (part == 0) {
        float* ip = idx_out + grow * NTOP;
        *(float4*)(ip)     = make_float4((float)idxs[0], (float)idxs[1],
                                         (float)idxs[2], (float)idxs[3]);
        *(float4*)(ip + 4) = make_float4((float)idxs[4], (float)idxs[5],
                                         (float)idxs[6], (float)idxs[7]);
    }

    // softmax over selected 8 (vals[0] is the row max)
    const float m0 = vals[0];
    float p[NTOP];
    float s = 0.0f;
#pragma unroll
    for (int k = 0; k < NTOP; ++k) { p[k] = expf(vals[k] - m0); s += p[k]; }
    const float inv = 1.0f / s;
#pragma unroll
    for (int k = 0; k < NTOP; ++k) p[k] *= inv;

    // sparse row: zeros except top-k
    float sv[8];
#pragma unroll
    for (int i = 0; i < 8; ++i) {
        float tv = 0.0f;
#pragma unroll
        for (int k = 0; k < NTOP; ++k)
            tv = (idxs[k] == part * 8 + i) ? p[k] : tv;
        sv[i] = tv;
    }
    {
        float* spt = sparse_out + grow * EDIM + part * 8;
        *(float4*)(spt)     = make_float4(sv[0], sv[1], sv[2], sv[3]);
        *(float4*)(spt + 4) = make_float4(sv[4], sv[5], sv[6], sv[7]);
    }
}

extern "C" void kernel_launch(void* const* d_in, const int* in_sizes, int n_in,
                              void* d_out, int out_size, void* d_ws, size_t ws_size,
                              hipStream_t stream)
{
    const float* x = (const float*)d_in[0];
    const float* W = (const float*)d_in[1];
    const float* b = (const float*)d_in[2];

    const int rows = in_sizes[0] / HDIM;   // B*S = 16384

    float* sparse = (float*)d_out;                                 // rows*64
    float* idx    = (float*)d_out + (size_t)rows * EDIM;           // rows*8
    float* gate   = (float*)d_out + (size_t)rows * EDIM
                                  + (size_t)rows * NTOP;           // rows*64

    dim3 grid(rows / ROWS), block(512);
    hipLaunchKernelGGL(gating_kernel, grid, block, 0, stream,
                       x, W, b, sparse, idx, gate);
}

// Round 5
// 568.014 us; speedup vs baseline: 1.8714x; 1.0619x over previous
//
#include <hip/hip_runtime.h>
#include <math.h>

#define HDIM 4096
#define EDIM 64
#define NTOP 8
#define KT 64                     // k-chunk staged per block
#define NC (HDIM / KT)            // 64 chunks
#define ROWS 64                   // rows per block (lane = row)
#define XSTRIDE 68                // padded LDS row stride (floats)
#define BUFSZ (ROWS * XSTRIDE)    // one staging buffer
#define LGSTRIDE 72               // logits gather stride

typedef float v2f __attribute__((ext_vector_type(2)));

// Block = 1024 threads = 16 waves; 64 rows (lane = row across every wave).
// wave = eg*? -> eg = wave&3 (expert group of 16), kg = wave>>2 (k quarter
// of each chunk). W addresses uniform per wave -> s_load (scalar pipe);
// x staged global->LDS coalesced, double-buffered; lane reads only its
// row's k-quarter (4x less LDS duplication than 8-wave full-chunk).
__global__ __launch_bounds__(1024, 1)
void gating_kernel(const float* __restrict__ x,
                   const float* __restrict__ W,
                   const float* __restrict__ bias,
                   float* __restrict__ sparse_out,
                   float* __restrict__ idx_out,
                   float* __restrict__ gate_out)
{
    __shared__ float SH[2 * BUFSZ];           // 34.8 KB x staging
    __shared__ float LG[ROWS * LGSTRIDE];     // 18.4 KB gathered logits

    const int t    = threadIdx.x;
    const int lane = t & 63;
    const int wave = t >> 6;
    const int uw   = __builtin_amdgcn_readfirstlane(wave);
    const int eg   = uw & 3;                  // expert group (16 experts)
    const int kg   = uw >> 2;                 // k quarter within each chunk

    // staging: 1024 threads x one float4 = 64 rows x 64 floats per chunk
    const int srow = t >> 4;                  // 0..63
    const int sp   = t & 15;                  // 0..15
    const float* gx = x + ((size_t)blockIdx.x * ROWS + srow) * HDIM + sp * 4;
    float* const xdst = &SH[srow * XSTRIDE + sp * 4];

    const float* wbase = W + (size_t)(eg * 16) * HDIM;   // uniform

    v2f acc[16];
#pragma unroll
    for (int e = 0; e < 16; ++e) acc[e] = (v2f){0.0f, 0.0f};

    // prologue: stage chunk 0; prefetch chunk 1 into regs
    float4 RA = *(const float4*)(gx);
    *(float4*)(xdst) = RA;
    __syncthreads();
    RA = *(const float4*)(gx + KT);

#pragma unroll 1
    for (int c = 0; c < NC; ++c) {
        if (c + 1 < NC) {                      // write chunk c+1
            *(float4*)(xdst + ((c + 1) & 1) * BUFSZ) = RA;
        }
        if (c + 2 < NC) {                      // issue loads for chunk c+2
            RA = *(const float4*)(gx + (c + 2) * KT);
        }

        // compute chunk c, k quarter kg, experts [16eg, 16eg+16)
        const float* xs = &SH[(c & 1) * BUFSZ + lane * XSTRIDE + kg * 16];
        float4 xv[4];
#pragma unroll
        for (int j = 0; j < 4; ++j) xv[j] = *(const float4*)(xs + 4 * j);

        const float* wc = wbase + c * KT + kg * 16;
#pragma unroll
        for (int e = 0; e < 16; ++e) {
            const float* we = wc + (size_t)e * HDIM;     // uniform
#pragma unroll
            for (int j = 0; j < 4; ++j) {
                const float4 wv = *(const float4*)(we + 4 * j);
                acc[e] = __builtin_elementwise_fma((v2f){xv[j].x, xv[j].y},
                                                   (v2f){wv.x, wv.y}, acc[e]);
                acc[e] = __builtin_elementwise_fma((v2f){xv[j].z, xv[j].w},
                                                   (v2f){wv.z, wv.w}, acc[e]);
            }
        }
        __syncthreads();
    }

    // ---- kg-reduction into LG[row][expert] (4 barrier-stepped adds) ----
    float part[16];
#pragma unroll
    for (int e = 0; e < 16; ++e) part[e] = acc[e].x + acc[e].y;

#pragma unroll
    for (int s = 0; s < 4; ++s) {
        if (kg == s) {
            float* dst = &LG[lane * LGSTRIDE + eg * 16];
            if (s == 0) {
#pragma unroll
                for (int e = 0; e < 16; ++e) dst[e] = part[e];
            } else {
#pragma unroll
                for (int e = 0; e < 16; ++e) dst[e] += part[e];
            }
        }
        __syncthreads();
    }

    if (wave >= 8) return;

    // ---- distributed epilogue (verified): wave uw rows [8uw,8uw+8), 8 lanes/row
    const int rp   = lane >> 3;
    const int part8 = lane & 7;
    const int row  = uw * 8 + rp;
    const size_t grow = (size_t)blockIdx.x * ROWS + row;

    const float* lr = &LG[row * LGSTRIDE + part8 * 8];
    const float4 va = *(const float4*)(lr);
    const float4 vb = *(const float4*)(lr + 4);
    float v[8] = {va.x, va.y, va.z, va.w, vb.x, vb.y, vb.z, vb.w};
    const float* bb = bias + part8 * 8;
#pragma unroll
    for (int j = 0; j < 8; ++j) v[j] += bb[j];

    // gate_logit = biased logits
    {
        float* g = gate_out + grow * EDIM + part8 * 8;
        *(float4*)(g)     = make_float4(v[0], v[1], v[2], v[3]);
        *(float4*)(g + 4) = make_float4(v[4], v[5], v[6], v[7]);
    }

    // top-8: local strict-'>' ascending scan then 8-lane butterfly
    // (ties -> lower index) == jax.lax.top_k order
    float vals[NTOP];
    int   idxs[NTOP];
#pragma unroll
    for (int k = 0; k < NTOP; ++k) {
        float bv = v[0];
        int   bi = part8 * 8;
#pragma unroll
        for (int i = 1; i < 8; ++i) {
            const bool g = v[i] > bv;
            bv = g ? v[i] : bv;
            bi = g ? part8 * 8 + i : bi;
        }
#pragma unroll
        for (int m = 1; m < 8; m <<= 1) {
            const float ov = __shfl_xor(bv, m);
            const int   oi = __shfl_xor(bi, m);
            const bool take = (ov > bv) || (ov == bv && oi < bi);
            bv = take ? ov : bv;
            bi = take ? oi : bi;
        }
        vals[k] = bv;
        idxs[k] = bi;
#pragma unroll
        for (int i = 0; i < 8; ++i)
            v[i] = (bi == part8 * 8 + i) ? -INFINITY : v[i];
    }

    // indices as float VALUES (harness reads d_out as f32)
    if (part8 == 0) {
        float* ip = idx_out + grow * NTOP;
        *(float4*)(ip)     = make_float4((float)idxs[0], (float)idxs[1],
                                         (float)idxs[2], (float)idxs[3]);
        *(float4*)(ip + 4) = make_float4((float)idxs[4], (float)idxs[5],
                                         (float)idxs[6], (float)idxs[7]);
    }

    // softmax over selected 8 (vals[0] is the row max)
    const float m0 = vals[0];
    float p[NTOP];
    float s = 0.0f;
#pragma unroll
    for (int k = 0; k < NTOP; ++k) { p[k] = expf(vals[k] - m0); s += p[k]; }
    const float inv = 1.0f / s;
#pragma unroll
    for (int k = 0; k < NTOP; ++k) p[k] *= inv;

    // sparse row: zeros except top-k
    float sv[8];
#pragma unroll
    for (int i = 0; i < 8; ++i) {
        float tv = 0.0f;
#pragma unroll
        for (int k = 0; k < NTOP; ++k)
            tv = (idxs[k] == part8 * 8 + i) ? p[k] : tv;
        sv[i] = tv;
    }
    {
        float* spt = sparse_out + grow * EDIM + part8 * 8;
        *(float4*)(spt)     = make_float4(sv[0], sv[1], sv[2], sv[3]);
        *(float4*)(spt + 4) = make_float4(sv[4], sv[5], sv[6], sv[7]);
    }
}

extern "C" void kernel_launch(void* const* d_in, const int* in_sizes, int n_in,
                              void* d_out, int out_size, void* d_ws, size_t ws_size,
                              hipStream_t stream)
{
    const float* x = (const float*)d_in[0];
    const float* W = (const float*)d_in[1];
    const float* b = (const float*)d_in[2];

    const int rows = in_sizes[0] / HDIM;   // B*S = 16384

    float* sparse = (float*)d_out;                                 // rows*64
    float* idx    = (float*)d_out + (size_t)rows * EDIM;           // rows*8
    float* gate   = (float*)d_out + (size_t)rows * EDIM
                                  + (size_t)rows * NTOP;           // rows*64

    dim3 grid(rows / ROWS), block(1024);
    hipLaunchKernelGGL(gating_kernel, grid, block, 0, stream,
                       x, W, b, sparse, idx, gate);
}

// Round 6
// 424.930 us; speedup vs baseline: 2.5015x; 1.3367x over previous
//
#include <hip/hip_runtime.h>
#include <math.h>

#define HDIM 4096
#define EDIM 64
#define NTOP 8
#define KT 64                     // k-chunk staged per block
#define NC (HDIM / KT)            // 64 chunks
#define ROWS 64                   // rows per block (lane = row)
#define XSTRIDE 68                // padded LDS row stride (floats), b128-aligned
#define BUFSZ (ROWS * XSTRIDE)    // one staging buffer (x or W)
#define LGSTRIDE 72               // logits gather stride

typedef float v2f __attribute__((ext_vector_type(2)));

// Block = 1024 threads = 16 waves; 64 rows (lane = row in every wave).
// wave -> eg = wave&3 (expert group of 16), kg = wave>>2 (k quarter of chunk).
// BOTH x and W staged global->LDS (coalesced, double-buffered). Compute:
// x via lane-varying ds_read_b128; W via uniform-address ds_read_b128
// (HW broadcast, conflict-free, imm offsets) -> no scalar-pipe latency chain.
__global__ __launch_bounds__(1024, 1)
void gating_kernel(const float* __restrict__ x,
                   const float* __restrict__ W,
                   const float* __restrict__ bias,
                   float* __restrict__ sparse_out,
                   float* __restrict__ idx_out,
                   float* __restrict__ gate_out)
{
    __shared__ float XS[2 * BUFSZ];           // 34.8 KB x staging
    __shared__ float WS[2 * BUFSZ];           // 34.8 KB W staging
    __shared__ float LG[ROWS * LGSTRIDE];     // 18.4 KB gathered logits

    const int t    = threadIdx.x;
    const int lane = t & 63;
    const int wave = t >> 6;
    const int uw   = __builtin_amdgcn_readfirstlane(wave);
    const int eg   = uw & 3;                  // expert group (16 experts)
    const int kg   = uw >> 2;                 // k quarter within each chunk

    // staging: 1024 threads x one float4 each for x and for W per chunk
    const int srow = t >> 4;                  // 0..63 (x row / W expert)
    const int sp   = t & 15;                  // float4 slot within 64-float row
    const float* gx = x + ((size_t)blockIdx.x * ROWS + srow) * HDIM + sp * 4;
    const float* gw = W + (size_t)srow * HDIM + sp * 4;
    float* const xdst = &XS[srow * XSTRIDE + sp * 4];
    float* const wdst = &WS[srow * XSTRIDE + sp * 4];

    v2f acc[16];
#pragma unroll
    for (int e = 0; e < 16; ++e) acc[e] = (v2f){0.0f, 0.0f};

    // prologue: stage chunk 0; prefetch chunk 1 into regs
    float4 RX = *(const float4*)(gx);
    float4 RW = *(const float4*)(gw);
    *(float4*)(xdst) = RX;
    *(float4*)(wdst) = RW;
    __syncthreads();
    RX = *(const float4*)(gx + KT);
    RW = *(const float4*)(gw + KT);

#pragma unroll 1
    for (int c = 0; c < NC; ++c) {
        if (c + 1 < NC) {                      // write chunk c+1
            const int b = ((c + 1) & 1) * BUFSZ;
            *(float4*)(xdst + b) = RX;
            *(float4*)(wdst + b) = RW;
        }
        if (c + 2 < NC) {                      // issue loads for chunk c+2
            RX = *(const float4*)(gx + (c + 2) * KT);
            RW = *(const float4*)(gw + (c + 2) * KT);
        }

        // compute chunk c: experts [16eg,16eg+16), k quarter kg
        const int b = (c & 1) * BUFSZ;
        const float* xs = &XS[b + lane * XSTRIDE + kg * 16];
        float4 xv[4];
#pragma unroll
        for (int j = 0; j < 4; ++j) xv[j] = *(const float4*)(xs + 4 * j);

        const float* ws = &WS[b + (eg * 16) * XSTRIDE + kg * 16];
#pragma unroll
        for (int e = 0; e < 16; ++e) {
            const float* we = ws + e * XSTRIDE;     // uniform addr -> broadcast
#pragma unroll
            for (int j = 0; j < 4; ++j) {
                const float4 wv = *(const float4*)(we + 4 * j);
                acc[e] = __builtin_elementwise_fma((v2f){xv[j].x, xv[j].y},
                                                   (v2f){wv.x, wv.y}, acc[e]);
                acc[e] = __builtin_elementwise_fma((v2f){xv[j].z, xv[j].w},
                                                   (v2f){wv.z, wv.w}, acc[e]);
            }
        }
        __syncthreads();
    }

    // ---- kg-reduction into LG[row][expert] (4 barrier-stepped adds) ----
    float part[16];
#pragma unroll
    for (int e = 0; e < 16; ++e) part[e] = acc[e].x + acc[e].y;

#pragma unroll
    for (int s = 0; s < 4; ++s) {
        if (kg == s) {
            float* dst = &LG[lane * LGSTRIDE + eg * 16];
            if (s == 0) {
#pragma unroll
                for (int e = 0; e < 16; ++e) dst[e] = part[e];
            } else {
#pragma unroll
                for (int e = 0; e < 16; ++e) dst[e] += part[e];
            }
        }
        __syncthreads();
    }

    if (wave >= 8) return;

    // ---- distributed epilogue (verified): wave uw rows [8uw,8uw+8), 8 lanes/row
    const int rp    = lane >> 3;
    const int part8 = lane & 7;
    const int row   = uw * 8 + rp;
    const size_t grow = (size_t)blockIdx.x * ROWS + row;

    const float* lr = &LG[row * LGSTRIDE + part8 * 8];
    const float4 va = *(const float4*)(lr);
    const float4 vb = *(const float4*)(lr + 4);
    float v[8] = {va.x, va.y, va.z, va.w, vb.x, vb.y, vb.z, vb.w};
    const float* bb = bias + part8 * 8;
#pragma unroll
    for (int j = 0; j < 8; ++j) v[j] += bb[j];

    // gate_logit = biased logits
    {
        float* g = gate_out + grow * EDIM + part8 * 8;
        *(float4*)(g)     = make_float4(v[0], v[1], v[2], v[3]);
        *(float4*)(g + 4) = make_float4(v[4], v[5], v[6], v[7]);
    }

    // top-8: local strict-'>' ascending scan then 8-lane butterfly
    // (ties -> lower index) == jax.lax.top_k order
    float vals[NTOP];
    int   idxs[NTOP];
#pragma unroll
    for (int k = 0; k < NTOP; ++k) {
        float bv = v[0];
        int   bi = part8 * 8;
#pragma unroll
        for (int i = 1; i < 8; ++i) {
            const bool g = v[i] > bv;
            bv = g ? v[i] : bv;
            bi = g ? part8 * 8 + i : bi;
        }
#pragma unroll
        for (int m = 1; m < 8; m <<= 1) {
            const float ov = __shfl_xor(bv, m);
            const int   oi = __shfl_xor(bi, m);
            const bool take = (ov > bv) || (ov == bv && oi < bi);
            bv = take ? ov : bv;
            bi = take ? oi : bi;
        }
        vals[k] = bv;
        idxs[k] = bi;
#pragma unroll
        for (int i = 0; i < 8; ++i)
            v[i] = (bi == part8 * 8 + i) ? -INFINITY : v[i];
    }

    // indices as float VALUES (harness reads d_out as f32)
    if (part8 == 0) {
        float* ip = idx_out + grow * NTOP;
        *(float4*)(ip)     = make_float4((float)idxs[0], (float)idxs[1],
                                         (float)idxs[2], (float)idxs[3]);
        *(float4*)(ip + 4) = make_float4((float)idxs[4], (float)idxs[5],
                                         (float)idxs[6], (float)idxs[7]);
    }

    // softmax over selected 8 (vals[0] is the row max)
    const float m0 = vals[0];
    float p[NTOP];
    float s = 0.0f;
#pragma unroll
    for (int k = 0; k < NTOP; ++k) { p[k] = expf(vals[k] - m0); s += p[k]; }
    const float inv = 1.0f / s;
#pragma unroll
    for (int k = 0; k < NTOP; ++k) p[k] *= inv;

    // sparse row: zeros except top-k
    float sv[8];
#pragma unroll
    for (int i = 0; i < 8; ++i) {
        float tv = 0.0f;
#pragma unroll
        for (int k = 0; k < NTOP; ++k)
            tv = (idxs[k] == part8 * 8 + i) ? p[k] : tv;
        sv[i] = tv;
    }
    {
        float* spt = sparse_out + grow * EDIM + part8 * 8;
        *(float4*)(spt)     = make_float4(sv[0], sv[1], sv[2], sv[3]);
        *(float4*)(spt + 4) = make_float4(sv[4], sv[5], sv[6], sv[7]);
    }
}

extern "C" void kernel_launch(void* const* d_in, const int* in_sizes, int n_in,
                              void* d_out, int out_size, void* d_ws, size_t ws_size,
                              hipStream_t stream)
{
    const float* x = (const float*)d_in[0];
    const float* W = (const float*)d_in[1];
    const float* b = (const float*)d_in[2];

    const int rows = in_sizes[0] / HDIM;   // B*S = 16384

    float* sparse = (float*)d_out;                                 // rows*64
    float* idx    = (float*)d_out + (size_t)rows * EDIM;           // rows*8
    float* gate   = (float*)d_out + (size_t)rows * EDIM
                                  + (size_t)rows * NTOP;           // rows*64

    dim3 grid(rows / ROWS), block(1024);
    hipLaunchKernelGGL(gating_kernel, grid, block, 0, stream,
                       x, W, b, sparse, idx, gate);
}